// Round 11
// baseline (2526.848 us; speedup 1.0000x reference)
//
#include <hip/hip_runtime.h>
#include <hip/hip_bf16.h>

#define BDIM 64
#define TDIM 360
#define BT (BDIM*TDIM)        // 23040
#define CDIM 128
#define HWSZ 1024
#define SDIM 64
#define G4 512
#define KTOP 160

typedef __hip_bfloat16 bf16;

static __device__ __forceinline__ unsigned int f2bu(float x) {
    bf16 b = __float2bfloat16(x);
    unsigned short u; __builtin_memcpy(&u, &b, 2); return (unsigned int)u;
}
static __device__ __forceinline__ float b2f(bf16 x) { return __bfloat162float(x); }
static __device__ __forceinline__ float bl(unsigned int u) { return __uint_as_float(u << 16); }
static __device__ __forceinline__ float bh(unsigned int u) { return __uint_as_float(u & 0xffff0000u); }
static __device__ __forceinline__ float tanh_fast(float x) {
    float e = __expf(2.0f * x);
    return 1.0f - 2.0f / (e + 1.0f);
}
static __device__ __forceinline__ float sigm(float x) {
    return 1.0f / (1.0f + __expf(-x));
}

// ---- static device workspace ----
__device__ float        g_ArowsF[BT * KTOP];   // [x_emb(32) | in_seq(128)] fp32
__device__ float        g_pre2[BT * G4];       // precomputed non-recurrent gate part
// folded recurrent weights, bf16 pairs, streaming layout:
// uint4 index jblk*1024 + u ; u = kh*512 + n ; covers K-pairs kh*64+jblk*4+{0..3}
__device__ __align__(16) unsigned int g_wpk2[16 * 1024 * 4];
__device__ float        g_penc[BDIM * SDIM * 64];
__device__ float        g_hatt[BT * 256];      // [h(128) | att(128)] per (b,t)
__device__ float        g_Wao[256 * 5];
__device__ float        g_bao[5];
__device__ float        g_bias[G4];
__device__ float        g_c0[G4];

// ---- A1: build [x_emb | gathered feature] rows ----
__global__ void kA1(const float* __restrict__ tok, const float* __restrict__ feat,
                    const float* __restrict__ Wemb, const float* __restrict__ bemb) {
    int row  = blockIdx.x * 4 + (threadIdx.x >> 6);
    int lane = threadIdx.x & 63;
    const float* tp = tok + (size_t)row * 4;
    float t0 = tp[0], t1 = tp[1], t2 = tp[2], t3 = tp[3];
    int b = row / TDIM;
    int x = (int)(t0 * 100.0f);
    int y = (int)(t1 * 100.0f);
    x = min(max(x, 0), 31);
    y = min(max(y, 0), 31);
    int idx = y * 32 + x;
    float* out = g_ArowsF + (size_t)row * KTOP;
    if (lane < 32) {
        float e = t0 * Wemb[lane] + t1 * Wemb[32 + lane] +
                  t2 * Wemb[64 + lane] + t3 * Wemb[96 + lane] + bemb[lane];
        out[lane] = e;
    }
    const float* fb = feat + (size_t)b * CDIM * HWSZ + idx;
    out[32 + lane]      = fb[(size_t)lane * HWSZ];
    out[32 + 64 + lane] = fb[(size_t)(64 + lane) * HWSZ];
}

// ---- A2a: fold recurrent weights into streaming layout ----
__global__ void kA2a(const float* __restrict__ Wih, const float* __restrict__ Whh,
                     const float* __restrict__ Waap) {
    __shared__ float sa0[128], sa1[128];
    int p = blockIdx.x, n = threadIdx.x;
    int r0 = 2 * p, r1 = 2 * p + 1;
    if (n < 128)            sa0[n]        = Waap[r0 * 128 + n];
    else if (n < 256)       sa1[n - 128]  = Waap[r1 * 128 + (n - 128)];
    __syncthreads();
    float acc0 = (r0 < 128) ? Whh[r0 * G4 + n] : 0.0f;
    float acc1 = (r1 < 128) ? Whh[r1 * G4 + n] : 0.0f;
    for (int j = 0; j < 128; ++j) {
        float wi = Wih[(160 + j) * G4 + n];
        acc0 += sa0[j] * wi;
        acc1 += sa1[j] * wi;
    }
    int kh = p >> 6, j = p & 63;
    int jblk = j >> 2, jj = j & 3;
    int u = kh * 512 + n;
    g_wpk2[((size_t)jblk * 1024 + u) * 4 + jj] = f2bu(acc0) | (f2bu(acc1) << 16);
}

// ---- A2c: bias vectors, c0, Wao, bao ----
__global__ void kA2c(const float* __restrict__ bih, const float* __restrict__ bhh,
                     const float* __restrict__ Wih, const float* __restrict__ Waap,
                     const float* __restrict__ baap, const float* __restrict__ Wout,
                     const float* __restrict__ bout) {
    __shared__ float sb[128];
    int n = threadIdx.x;
    if (n < 128) sb[n] = baap[n];
    __syncthreads();
    g_bias[n] = bih[n] + bhh[n];
    float c0 = 0.0f;
    for (int j = 0; j < 128; ++j) c0 += sb[j] * Wih[(160 + j) * G4 + n];
    g_c0[n] = c0;
    if (n < 256) {
        for (int o = 0; o < 5; ++o) {
            float acc = 0.0f;
            for (int j = 0; j < 128; ++j) acc += Waap[n * 128 + j] * Wout[j * 5 + o];
            g_Wao[n * 5 + o] = acc;
        }
    }
    if (n == 0) {
        for (int o = 0; o < 5; ++o) {
            float acc = bout[o];
            for (int j = 0; j < 128; ++j) acc += sb[j] * Wout[j * 5 + o];
            g_bao[o] = acc;
        }
    }
}

// ---- A2d: p_enc ----
__global__ void kA2d(const float* __restrict__ FH, const float* __restrict__ Wep,
                     const float* __restrict__ bep) {
    __shared__ float sfh[128 * 64];
    int b = blockIdx.x, tid = threadIdx.x;
    for (int i = tid; i < 128 * 64; i += 256) sfh[i] = FH[(size_t)b * 128 * 64 + i];
    __syncthreads();
    int a = tid & 63, sg = tid >> 6;
    float bias = bep[a];
    float acc[16];
#pragma unroll
    for (int i = 0; i < 16; ++i) acc[i] = bias;
    for (int d = 0; d < 128; ++d) {
        float wa = Wep[d * 64 + a];
#pragma unroll
        for (int i = 0; i < 16; ++i) acc[i] += sfh[d * 64 + sg * 16 + i] * wa;
    }
    for (int i = 0; i < 16; ++i)
        g_penc[((size_t)b * 64 + sg * 16 + i) * 64 + a] = acc[i];
}

// ---- B: pre2 = Arows @ W_ih[0:160] ----
__global__ void __attribute__((amdgpu_flat_work_group_size(512, 512),
                               amdgpu_waves_per_eu(2, 2)))
kB(const float* __restrict__ Wih) {
    int n = threadIdx.x;
    int m0 = blockIdx.x * 8;
    float racc[8];
#pragma unroll
    for (int r = 0; r < 8; ++r) racc[r] = 0.0f;
#pragma unroll 1
    for (int pass = 0; pass < 2; ++pass) {
        float wcol[80];
#pragma unroll
        for (int j = 0; j < 80; ++j) wcol[j] = Wih[(pass * 80 + j) * G4 + n];
#pragma unroll
        for (int r = 0; r < 8; ++r) {
            const float4* rp = (const float4*)(g_ArowsF + (size_t)(m0 + r) * KTOP + pass * 80);
            float a0 = 0.f, a1 = 0.f, a2 = 0.f, a3 = 0.f;
#pragma unroll
            for (int q = 0; q < 20; ++q) {
                float4 v = rp[q];
                a0 += wcol[4 * q + 0] * v.x;
                a1 += wcol[4 * q + 1] * v.y;
                a2 += wcol[4 * q + 2] * v.z;
                a3 += wcol[4 * q + 3] * v.w;
            }
            racc[r] += (a0 + a1) + (a2 + a3);
        }
    }
#pragma unroll
    for (int r = 0; r < 8; ++r)
        g_pre2[(size_t)(m0 + r) * G4 + n] = racc[r];
}

// Dual-element consume: unpack each bf16 weight ONCE, FMA into both elements.
#define CONS2(W, jb) { \
    float4 a0v = vA[2 * (jb)], a1v = vA[2 * (jb) + 1]; \
    float4 b0v = vB[2 * (jb)], b1v = vB[2 * (jb) + 1]; \
    float w; \
    w = bl(W.x); accA0 += w * a0v.x; accB0 += w * b0v.x; \
    w = bh(W.x); accA1 += w * a0v.y; accB1 += w * b0v.y; \
    w = bl(W.y); accA0 += w * a0v.z; accB0 += w * b0v.z; \
    w = bh(W.y); accA1 += w * a0v.w; accB1 += w * b0v.w; \
    w = bl(W.z); accA0 += w * a1v.x; accB0 += w * b1v.x; \
    w = bh(W.z); accA1 += w * a1v.y; accB1 += w * b1v.y; \
    w = bl(W.w); accA0 += w * a1v.z; accB0 += w * b1v.z; \
    w = bh(W.w); accA1 += w * a1v.w; accB1 += w * b1v.w; }
#define LDP(R, jb)  R = wp[(jb) * 1024];          // kh=0 half (vs h)
#define LDQ(R, jb)  R = wp[(jb) * 1024 + 512];    // kh=1 half (vs att)
#define SB __builtin_amdgcn_sched_barrier(0);

// Single-element 8-MAC consume (for atth with register weights from LDS row)
#define CONSA(W, jb) { \
    float4 v0 = vals[2 * (jb)], v1 = vals[2 * (jb) + 1]; \
    acc0 += bl(W.x) * v0.x;  acc1 += bh(W.x) * v0.y; \
    acc0 += bl(W.y) * v0.z;  acc1 += bh(W.y) * v0.w; \
    acc0 += bl(W.z) * v1.x;  acc1 += bh(W.z) * v1.y; \
    acc0 += bl(W.w) * v1.z;  acc1 += bh(W.w) * v1.w; }

// ---- C: sequential recurrence, 512 threads/block, TWO batch elements/block ----
// Round-11: the weight stream (256 KB/step, L1-port-bound ~4096 cyc — rounds
// 7-10 showed prefetch can't compress it) is identical for all batch elements.
// Fold 2 elements per block: one stream serves two dots (unpack once, 2 FMAs),
// tails run element-parallel on wave halves. 32 blocks total.
// Dynamic LDS (~87.5 KB: penc f32 + encp bf16 + w2aT bf16, per-element dup).
__global__ void __launch_bounds__(512) kC(const float* __restrict__ FH,
                                          const float* __restrict__ W2a,
                                          const float* __restrict__ Walpha,
                                          const float* __restrict__ balpha,
                                          const float* __restrict__ bh2a) {
    __shared__ __align__(16) float s_val[512];   // [e][h(128)|att(128)]
    __shared__ float s_c[256];                   // [e][128]
    __shared__ float s_gates[1024];              // [e][512]
    __shared__ float s_atth[128];                // [e][64]
    __shared__ float s_scores[128];
    __shared__ float s_wgt[128];
    __shared__ float s_walpha[64];
    __shared__ float s_bh2a[64];
    extern __shared__ __align__(16) char dsm[];
    float* s_penc = (float*)dsm;                         // [e][64*65]  33280 B
    bf16*  s_encp = (bf16*)(dsm + 33280);                // [e][128*72] 36864 B
    bf16*  s_w2aT = (bf16*)(dsm + 33280 + 36864);        // [64*136]    17408 B

    int tid = threadIdx.x;
    int b0 = blockIdx.x * 2;
    int n = tid;                                 // gate output, full K, both elems
    int e  = tid >> 8;                           // element for tail phases
    int et = tid & 255;                          // thread-in-element

    const uint4* wp = ((const uint4*)g_wpk2) + n;

    uint4 P0,P1,P2,P3,P4,P5,P6,P7,P8,P9,P10,P11,P12,P13,P14,P15;
    LDP(P0,0)  LDP(P1,1)  LDP(P2,2)  LDP(P3,3)
    LDP(P4,4)  LDP(P5,5)  LDP(P6,6)  LDP(P7,7)
    LDP(P8,8)  LDP(P9,9)  LDP(P10,10) LDP(P11,11)
    LDP(P12,12) LDP(P13,13) LDP(P14,14) LDP(P15,15)
    SB

    float bias_r = g_bias[n];
    float bc_r   = bias_r + g_c0[n];

    s_val[tid] = 0.0f;
    if (tid < 256) s_c[tid] = 0.0f;
    if (tid < 64) { s_walpha[tid] = Walpha[tid]; s_bh2a[tid] = bh2a[tid]; }
    for (int i = tid; i < 2 * 4096; i += 512) {
        int ee = i >> 12, r = i & 4095;
        int s = r >> 6, a = r & 63;
        s_penc[ee * 4160 + s * 65 + a] = g_penc[((size_t)(b0 + ee) * 64 + s) * 64 + a];
    }
    for (int i = tid; i < 2 * 8192; i += 512) {
        int ee = i >> 13, r = i & 8191;
        int d = r >> 6, s = r & 63;
        s_encp[ee * 9216 + d * 72 + s] = __float2bfloat16(FH[(size_t)(b0 + ee) * 8192 + r]);
    }
    for (int i = tid; i < 8192; i += 512) {
        int d = i >> 6, s = i & 63;
        s_w2aT[s * 136 + d] = __float2bfloat16(W2a[i]);
    }
    float bal = balpha[0];

    const float* pp = g_pre2 + (size_t)b0 * TDIM * G4 + n;       // elem A; B at +TDIM*G4
    float* hp = g_hatt + (size_t)(b0 + e) * TDIM * 256;          // this thread's tail elem

    for (int t = 0; t < TDIM; ++t) {
        __syncthreads();                 // (1) state(t-1) ready
        float p2a = pp[(size_t)t * G4];
        float p2b = pp[(size_t)TDIM * G4 + (size_t)t * G4];
        float accA0 = 0.f, accA1 = 0.f, accB0 = 0.f, accB1 = 0.f;
        const float4* vA = (const float4*)s_val;
        const float4* vB = (const float4*)(s_val + 256);
        uint4 Q0,Q1,Q2,Q3,Q4,Q5,Q6,Q7,Q8,Q9,Q10,Q11,Q12,Q13,Q14,Q15;
        LDQ(Q0,0)  LDQ(Q1,1)  LDQ(Q2,2)  LDQ(Q3,3)
        CONS2(P0,0)  CONS2(P1,1)  CONS2(P2,2)  CONS2(P3,3)
        SB
        LDQ(Q4,4)  LDQ(Q5,5)  LDQ(Q6,6)  LDQ(Q7,7)
        CONS2(P4,4)  CONS2(P5,5)  CONS2(P6,6)  CONS2(P7,7)
        SB
        LDQ(Q8,8)  LDQ(Q9,9)  LDQ(Q10,10) LDQ(Q11,11)
        CONS2(P8,8)  CONS2(P9,9)  CONS2(P10,10) CONS2(P11,11)
        SB
        LDQ(Q12,12) LDQ(Q13,13) LDQ(Q14,14) LDQ(Q15,15)
        CONS2(P12,12) CONS2(P13,13) CONS2(P14,14) CONS2(P15,15)
        SB
        CONS2(Q0,16)  CONS2(Q1,17)  CONS2(Q2,18)  CONS2(Q3,19)
        CONS2(Q4,20)  CONS2(Q5,21)  CONS2(Q6,22)  CONS2(Q7,23)
        CONS2(Q8,24)  CONS2(Q9,25)  CONS2(Q10,26) CONS2(Q11,27)
        CONS2(Q12,28) CONS2(Q13,29) CONS2(Q14,30) CONS2(Q15,31)
        float bb = (t ? bc_r : bias_r);
        s_gates[n]       = accA0 + accA1 + p2a + bb;
        s_gates[512 + n] = accB0 + accB1 + p2b + bb;
        SB
        // prefetch h-half for t+1 (lands during pw + tail)
        LDP(P0,0)  LDP(P1,1)  LDP(P2,2)  LDP(P3,3)
        LDP(P4,4)  LDP(P5,5)  LDP(P6,6)  LDP(P7,7)
        LDP(P8,8)  LDP(P9,9)  LDP(P10,10) LDP(P11,11)
        LDP(P12,12) LDP(P13,13) LDP(P14,14) LDP(P15,15)
        SB
        __syncthreads();                 // (2) gates ready
        // LSTM pointwise, element-parallel (gate order i,f,g,o)
        if (et < 128) {
            const float* sg = s_gates + e * 512;
            float gi = sg[et];
            float gf = sg[et + 128];
            float gg = sg[et + 256];
            float go = sg[et + 384];
            float c = sigm(gf) * s_c[e * 128 + et] + sigm(gi) * tanh_fast(gg);
            s_c[e * 128 + et] = c;
            float h = sigm(go) * tanh_fast(c);
            s_val[e * 256 + et] = h;
            hp[(size_t)t * 256 + et] = h;
        }
        __syncthreads();                 // (3) h ready
        // att_h[a] = h @ W2a[:,a] + bh2a[a] : 4-lane group per a, per element
        {
            int a = et >> 2, sub = et & 3;
            const float4* vals = (const float4*)(s_val + e * 256);
            const uint4* wr = (const uint4*)&s_w2aT[a * 136 + 32 * sub];
            uint4 w0 = wr[0], w1 = wr[1], w2 = wr[2], w3 = wr[3];
            float acc0 = 0.f, acc1 = 0.f;
            CONSA(w0, 4 * sub + 0) CONSA(w1, 4 * sub + 1)
            CONSA(w2, 4 * sub + 2) CONSA(w3, 4 * sub + 3)
            float acc = acc0 + acc1;
            acc += __shfl_xor(acc, 1);
            acc += __shfl_xor(acc, 2);
            if (sub == 0) s_atth[e * 64 + a] = acc + s_bh2a[a];
        }
        __syncthreads();                 // (4) atth ready
        // scores[s] = sum_a tanh(p_enc + att_h) * W_alpha : 4 lanes per s
        {
            int ss = et >> 2, sub = et & 3;
            const float* pe = s_penc + e * 4160 + ss * 65;
            const float* ah = s_atth + e * 64;
            float acc = 0.f;
#pragma unroll
            for (int j = 0; j < 16; ++j) {
                int a = sub * 16 + j;
                float xv = pe[a] + ah[a];
                acc += tanh_fast(xv) * s_walpha[a];
            }
            acc += __shfl_xor(acc, 1);
            acc += __shfl_xor(acc, 2);
            if (sub == 0) s_scores[e * 64 + ss] = acc + bal;
        }
        __syncthreads();                 // (5) scores ready
        if (et < 64) {                   // wave 0 (e=0) and wave 4 (e=1)
            float v = s_scores[e * 64 + et];
            float m = v;
#pragma unroll
            for (int off = 32; off > 0; off >>= 1) m = fmaxf(m, __shfl_xor(m, off));
            float ex = __expf(v - m);
            float sum = ex;
#pragma unroll
            for (int off = 32; off > 0; off >>= 1) sum += __shfl_xor(sum, off);
            s_wgt[e * 64 + et] = ex / sum;
        }
        __syncthreads();                 // (6) wgt ready
        // att_res[d] = sum_s wgt[s] * enc[d][s] : 2-lane group per d
        {
            int d = et >> 1, sub = et & 1;
            const uint4* er = (const uint4*)&s_encp[e * 9216 + d * 72 + 32 * sub];
            uint4 e0 = er[0], e1 = er[1], e2 = er[2], e3 = er[3];
            const float* wg = s_wgt + e * 64 + 32 * sub;
            float acc0 = 0.f, acc1 = 0.f;
            acc0 += bl(e0.x) * wg[0];   acc1 += bh(e0.x) * wg[1];
            acc0 += bl(e0.y) * wg[2];   acc1 += bh(e0.y) * wg[3];
            acc0 += bl(e0.z) * wg[4];   acc1 += bh(e0.z) * wg[5];
            acc0 += bl(e0.w) * wg[6];   acc1 += bh(e0.w) * wg[7];
            acc0 += bl(e1.x) * wg[8];   acc1 += bh(e1.x) * wg[9];
            acc0 += bl(e1.y) * wg[10];  acc1 += bh(e1.y) * wg[11];
            acc0 += bl(e1.z) * wg[12];  acc1 += bh(e1.z) * wg[13];
            acc0 += bl(e1.w) * wg[14];  acc1 += bh(e1.w) * wg[15];
            acc0 += bl(e2.x) * wg[16];  acc1 += bh(e2.x) * wg[17];
            acc0 += bl(e2.y) * wg[18];  acc1 += bh(e2.y) * wg[19];
            acc0 += bl(e2.z) * wg[20];  acc1 += bh(e2.z) * wg[21];
            acc0 += bl(e2.w) * wg[22];  acc1 += bh(e2.w) * wg[23];
            acc0 += bl(e3.x) * wg[24];  acc1 += bh(e3.x) * wg[25];
            acc0 += bl(e3.y) * wg[26];  acc1 += bh(e3.y) * wg[27];
            acc0 += bl(e3.z) * wg[28];  acc1 += bh(e3.z) * wg[29];
            acc0 += bl(e3.w) * wg[30];  acc1 += bh(e3.w) * wg[31];
            float acc = acc0 + acc1;
            acc += __shfl_xor(acc, 1);
            if (sub == 0) {
                s_val[e * 256 + 128 + d] = acc;
                hp[(size_t)t * 256 + 128 + d] = acc;
            }
        }
        // loop-top barrier covers s_val/s_gates reuse
    }
}

// ---- D: final out = [h|att] @ (W_aap@W_out) + bao, 4 rows/block ----
__global__ void kD(float* __restrict__ out) {
    int r = blockIdx.x * 4 + (threadIdx.x >> 6);
    int lane = threadIdx.x & 63;
    const float4* hv = (const float4*)(g_hatt + (size_t)r * 256);
    float4 v = hv[lane];
    int k0 = lane * 4;
    float acc[5];
#pragma unroll
    for (int o = 0; o < 5; ++o)
        acc[o] = v.x * g_Wao[(k0 + 0) * 5 + o] + v.y * g_Wao[(k0 + 1) * 5 + o] +
                 v.z * g_Wao[(k0 + 2) * 5 + o] + v.w * g_Wao[(k0 + 3) * 5 + o];
#pragma unroll
    for (int off = 32; off > 0; off >>= 1) {
#pragma unroll
        for (int o = 0; o < 5; ++o) acc[o] += __shfl_xor(acc[o], off);
    }
    if (lane == 0) {
#pragma unroll
        for (int o = 0; o < 5; ++o) out[(size_t)r * 5 + o] = acc[o] + g_bao[o];
    }
}

extern "C" void kernel_launch(void* const* d_in, const int* in_sizes, int n_in,
                              void* d_out, int out_size, void* d_ws, size_t ws_size,
                              hipStream_t stream) {
    (void)in_sizes; (void)n_in; (void)d_ws; (void)ws_size; (void)out_size;
    const float* tok  = (const float*)d_in[0];
    const float* feat = (const float*)d_in[1];
    const float* FH   = (const float*)d_in[2];
    const float* Wemb = (const float*)d_in[3];
    const float* bemb = (const float*)d_in[4];
    const float* Wih  = (const float*)d_in[5];
    const float* bih  = (const float*)d_in[6];
    const float* Whh  = (const float*)d_in[7];
    const float* bhh  = (const float*)d_in[8];
    const float* W2a  = (const float*)d_in[9];
    const float* bh2a = (const float*)d_in[10];
    const float* Wal  = (const float*)d_in[11];
    const float* bal  = (const float*)d_in[12];
    const float* Wep  = (const float*)d_in[13];
    const float* bep  = (const float*)d_in[14];
    const float* Waap = (const float*)d_in[15];
    const float* baap = (const float*)d_in[16];
    const float* Wout = (const float*)d_in[17];
    const float* bout = (const float*)d_in[18];
    float* out = (float*)d_out;

    const int kc_dyn_lds = 33280 + 36864 + 17408;    // 87552 B
    (void)hipFuncSetAttribute((const void*)kC,
                              hipFuncAttributeMaxDynamicSharedMemorySize,
                              kc_dyn_lds);

    kA1<<<dim3(BT / 4), dim3(256), 0, stream>>>(tok, feat, Wemb, bemb);
    kA2a<<<dim3(128), dim3(512), 0, stream>>>(Wih, Whh, Waap);
    kA2c<<<dim3(1), dim3(512), 0, stream>>>(bih, bhh, Wih, Waap, baap, Wout, bout);
    kA2d<<<dim3(64), dim3(256), 0, stream>>>(FH, Wep, bep);
    kB<<<dim3(BT / 8), dim3(512), 0, stream>>>(Wih);
    kC<<<dim3(32), dim3(512), kc_dyn_lds, stream>>>(FH, W2a, Wal, bal, bh2a);
    kD<<<dim3(BT / 4), dim3(256), 0, stream>>>(out);
}

// Round 12
// 1689.088 us; speedup vs baseline: 1.4960x; 1.4960x over previous
//
#include <hip/hip_runtime.h>
#include <hip/hip_bf16.h>

#define BDIM 64
#define TDIM 360
#define BT (BDIM*TDIM)        // 23040
#define CDIM 128
#define HWSZ 1024
#define SDIM 64
#define G4 512
#define KTOP 160

typedef __hip_bfloat16 bf16;

static __device__ __forceinline__ unsigned int f2bu(float x) {
    bf16 b = __float2bfloat16(x);
    unsigned short u; __builtin_memcpy(&u, &b, 2); return (unsigned int)u;
}
static __device__ __forceinline__ float b2f(bf16 x) { return __bfloat162float(x); }
static __device__ __forceinline__ float bl(unsigned int u) { return __uint_as_float(u << 16); }
static __device__ __forceinline__ float bh(unsigned int u) { return __uint_as_float(u & 0xffff0000u); }
static __device__ __forceinline__ float tanh_fast(float x) {
    float e = __expf(2.0f * x);
    return 1.0f - 2.0f / (e + 1.0f);
}
static __device__ __forceinline__ float sigm(float x) {
    return 1.0f / (1.0f + __expf(-x));
}

// ---- static device workspace ----
__device__ float        g_ArowsF[BT * KTOP];   // [x_emb(32) | in_seq(128)] fp32
__device__ float        g_pre2[BT * G4];       // precomputed non-recurrent gate part
// folded recurrent weights (h-half used), bf16 pairs, streaming layout (round 7)
__device__ __align__(16) unsigned int g_wpk2[16 * 1024 * 4];
__device__ float        g_wrecA[128 * G4];     // att-half fold, fp32 (for kA2e)
__device__ __align__(16) unsigned int g_encW2[BDIM * G4 * 32]; // encW[b][n][s2] bf16-pairs
__device__ float        g_encWao[BDIM * 64 * 5];
__device__ float        g_penc[BDIM * SDIM * 64];
__device__ float        g_hw[BT * 192];        // [h(128) | wgt(64)] per (b,t)
__device__ float        g_Wao[256 * 5];
__device__ float        g_bao[5];
__device__ float        g_bias[G4];
__device__ float        g_c0[G4];

// ---- A1: build [x_emb | gathered feature] rows ----
__global__ void kA1(const float* __restrict__ tok, const float* __restrict__ feat,
                    const float* __restrict__ Wemb, const float* __restrict__ bemb) {
    int row  = blockIdx.x * 4 + (threadIdx.x >> 6);
    int lane = threadIdx.x & 63;
    const float* tp = tok + (size_t)row * 4;
    float t0 = tp[0], t1 = tp[1], t2 = tp[2], t3 = tp[3];
    int b = row / TDIM;
    int x = (int)(t0 * 100.0f);
    int y = (int)(t1 * 100.0f);
    x = min(max(x, 0), 31);
    y = min(max(y, 0), 31);
    int idx = y * 32 + x;
    float* out = g_ArowsF + (size_t)row * KTOP;
    if (lane < 32) {
        float e = t0 * Wemb[lane] + t1 * Wemb[32 + lane] +
                  t2 * Wemb[64 + lane] + t3 * Wemb[96 + lane] + bemb[lane];
        out[lane] = e;
    }
    const float* fb = feat + (size_t)b * CDIM * HWSZ + idx;
    out[32 + lane]      = fb[(size_t)lane * HWSZ];
    out[32 + 64 + lane] = fb[(size_t)(64 + lane) * HWSZ];
}

// ---- A2a: fold recurrent weights; h-half packed for streaming, att-half fp32 ----
__global__ void kA2a(const float* __restrict__ Wih, const float* __restrict__ Whh,
                     const float* __restrict__ Waap) {
    __shared__ float sa0[128], sa1[128];
    int p = blockIdx.x, n = threadIdx.x;
    int r0 = 2 * p, r1 = 2 * p + 1;
    if (n < 128)            sa0[n]        = Waap[r0 * 128 + n];
    else if (n < 256)       sa1[n - 128]  = Waap[r1 * 128 + (n - 128)];
    __syncthreads();
    float acc0 = (r0 < 128) ? Whh[r0 * G4 + n] : 0.0f;
    float acc1 = (r1 < 128) ? Whh[r1 * G4 + n] : 0.0f;
    for (int j = 0; j < 128; ++j) {
        float wi = Wih[(160 + j) * G4 + n];
        acc0 += sa0[j] * wi;
        acc1 += sa1[j] * wi;
    }
    int kh = p >> 6, j = p & 63;
    int jblk = j >> 2, jj = j & 3;
    int u = kh * 512 + n;
    g_wpk2[((size_t)jblk * 1024 + u) * 4 + jj] = f2bu(acc0) | (f2bu(acc1) << 16);
    if (p >= 64) {                         // att-half rows, fp32 for kA2e fold
        g_wrecA[(r0 - 128) * G4 + n] = acc0;
        g_wrecA[(r1 - 128) * G4 + n] = acc1;
    }
}

// ---- A2c: bias vectors, c0, Wao, bao ----
__global__ void kA2c(const float* __restrict__ bih, const float* __restrict__ bhh,
                     const float* __restrict__ Wih, const float* __restrict__ Waap,
                     const float* __restrict__ baap, const float* __restrict__ Wout,
                     const float* __restrict__ bout) {
    __shared__ float sb[128];
    int n = threadIdx.x;
    if (n < 128) sb[n] = baap[n];
    __syncthreads();
    g_bias[n] = bih[n] + bhh[n];
    float c0 = 0.0f;
    for (int j = 0; j < 128; ++j) c0 += sb[j] * Wih[(160 + j) * G4 + n];
    g_c0[n] = c0;
    if (n < 256) {
        for (int o = 0; o < 5; ++o) {
            float acc = 0.0f;
            for (int j = 0; j < 128; ++j) acc += Waap[n * 128 + j] * Wout[j * 5 + o];
            g_Wao[n * 5 + o] = acc;
        }
    }
    if (n == 0) {
        for (int o = 0; o < 5; ++o) {
            float acc = bout[o];
            for (int j = 0; j < 128; ++j) acc += sb[j] * Wout[j * 5 + o];
            g_bao[o] = acc;
        }
    }
}

// ---- A2d: p_enc ----
__global__ void kA2d(const float* __restrict__ FH, const float* __restrict__ Wep,
                     const float* __restrict__ bep) {
    __shared__ float sfh[128 * 64];
    int b = blockIdx.x, tid = threadIdx.x;
    for (int i = tid; i < 128 * 64; i += 256) sfh[i] = FH[(size_t)b * 128 * 64 + i];
    __syncthreads();
    int a = tid & 63, sg = tid >> 6;
    float bias = bep[a];
    float acc[16];
#pragma unroll
    for (int i = 0; i < 16; ++i) acc[i] = bias;
    for (int d = 0; d < 128; ++d) {
        float wa = Wep[d * 64 + a];
#pragma unroll
        for (int i = 0; i < 16; ++i) acc[i] += sfh[d * 64 + sg * 16 + i] * wa;
    }
    for (int i = 0; i < 16; ++i)
        g_penc[((size_t)b * 64 + sg * 16 + i) * 64 + a] = acc[i];
}

// ---- A2e: encW[b] = enc[b] @ Wrec_att (bf16 pack), encWao[b] = enc[b] @ Wao_att ----
__global__ void kA2e(const float* __restrict__ FH) {
    __shared__ float encL[64][129];      // enc[s][d], padded
    int b = blockIdx.x, tid = threadIdx.x;
    for (int i = tid; i < 8192; i += 512) {
        int d = i >> 6, s = i & 63;
        encL[s][d] = FH[(size_t)b * 8192 + i];
    }
    __syncthreads();
    int n = tid;
#pragma unroll 1
    for (int sc = 0; sc < 8; ++sc) {
        float acc[8];
#pragma unroll
        for (int j = 0; j < 8; ++j) acc[j] = 0.f;
        for (int d = 0; d < 128; ++d) {
            float wv = g_wrecA[d * G4 + n];
#pragma unroll
            for (int j = 0; j < 8; ++j) acc[j] += encL[sc * 8 + j][d] * wv;
        }
#pragma unroll
        for (int j = 0; j < 4; ++j) {
            int s2 = sc * 4 + j;
            g_encW2[((size_t)b * G4 + n) * 32 + s2] =
                f2bu(acc[2 * j]) | (f2bu(acc[2 * j + 1]) << 16);
        }
    }
    if (tid < 64) {
        for (int o = 0; o < 5; ++o) {
            float acc = 0.f;
            for (int d = 0; d < 128; ++d)
                acc += encL[tid][d] * g_Wao[(128 + d) * 5 + o];
            g_encWao[((size_t)b * 64 + tid) * 5 + o] = acc;
        }
    }
}

// ---- B: pre2 = Arows @ W_ih[0:160] ----
__global__ void __attribute__((amdgpu_flat_work_group_size(512, 512),
                               amdgpu_waves_per_eu(2, 2)))
kB(const float* __restrict__ Wih) {
    int n = threadIdx.x;
    int m0 = blockIdx.x * 8;
    float racc[8];
#pragma unroll
    for (int r = 0; r < 8; ++r) racc[r] = 0.0f;
#pragma unroll 1
    for (int pass = 0; pass < 2; ++pass) {
        float wcol[80];
#pragma unroll
        for (int j = 0; j < 80; ++j) wcol[j] = Wih[(pass * 80 + j) * G4 + n];
#pragma unroll
        for (int r = 0; r < 8; ++r) {
            const float4* rp = (const float4*)(g_ArowsF + (size_t)(m0 + r) * KTOP + pass * 80);
            float a0 = 0.f, a1 = 0.f, a2 = 0.f, a3 = 0.f;
#pragma unroll
            for (int q = 0; q < 20; ++q) {
                float4 v = rp[q];
                a0 += wcol[4 * q + 0] * v.x;
                a1 += wcol[4 * q + 1] * v.y;
                a2 += wcol[4 * q + 2] * v.z;
                a3 += wcol[4 * q + 3] * v.w;
            }
            racc[r] += (a0 + a1) + (a2 + a3);
        }
    }
#pragma unroll
    for (int r = 0; r < 8; ++r)
        g_pre2[(size_t)(m0 + r) * G4 + n] = racc[r];
}

#define CONS1(W, jb) { \
    float4 v0 = vals[2 * (jb)], v1 = vals[2 * (jb) + 1]; \
    acc0 += bl(W.x) * v0.x;  acc1 += bh(W.x) * v0.y; \
    acc0 += bl(W.y) * v0.z;  acc1 += bh(W.y) * v0.w; \
    acc0 += bl(W.z) * v1.x;  acc1 += bh(W.z) * v1.y; \
    acc0 += bl(W.w) * v1.z;  acc1 += bh(W.w) * v1.w; }
#define LDP(R, jb)  R = wp[(jb) * 1024];          // h-half (kh=0)
#define SB __builtin_amdgcn_sched_barrier(0);

// ---- C: sequential recurrence, 512 threads/block, att eliminated from loop ----
// Round-12: att@Wrec_att = wgt@(enc@Wrec_att) = wgt@encW, encW [64x512] bf16
// precomputed per-block and LDS-RESIDENT. Weight stream halves (128 KB/step,
// h-half only); attres phase (heaviest tail phase) eliminated — out's
// att-contribution folded via encWao in kD. 5 barriers/step.
__global__ void __launch_bounds__(512) kC(const float* __restrict__ Walpha,
                                          const float* __restrict__ balpha,
                                          const float* __restrict__ bh2a,
                                          const float* __restrict__ W2a) {
    __shared__ __align__(16) float s_h[128];
    __shared__ float s_c[128];
    __shared__ float s_gates[512];
    __shared__ float s_atth[64];
    __shared__ float s_scores[64];
    __shared__ __align__(8) float s_wgt[64];
    __shared__ float s_walpha[64];
    __shared__ float s_bh2a[64];
    extern __shared__ __align__(16) char dsm[];
    unsigned int* s_encW = (unsigned int*)dsm;              // [512][34] u32  69632 B
    float* s_penc = (float*)(dsm + 69632);                  // [64][65] f32   16640 B
    bf16*  s_w2aT = (bf16*)(dsm + 69632 + 16640);           // [64][136] bf16 17408 B

    int tid = threadIdx.x;
    int b = blockIdx.x;
    int n = tid;

    const uint4* wp = ((const uint4*)g_wpk2) + n;   // h-half rows (kh=0 → u=n)

    uint4 P0,P1,P2,P3,P4,P5,P6,P7,P8,P9,P10,P11,P12,P13,P14,P15;
    LDP(P0,0)  LDP(P1,1)  LDP(P2,2)  LDP(P3,3)
    LDP(P4,4)  LDP(P5,5)  LDP(P6,6)  LDP(P7,7)
    LDP(P8,8)  LDP(P9,9)  LDP(P10,10) LDP(P11,11)
    LDP(P12,12) LDP(P13,13) LDP(P14,14) LDP(P15,15)
    SB

    float bias_r = g_bias[n];
    float bc_r   = bias_r + g_c0[n];

    if (tid < 128) { s_h[tid] = 0.0f; s_c[tid] = 0.0f; }
    if (tid < 64) { s_wgt[tid] = 0.0f; s_walpha[tid] = Walpha[tid]; s_bh2a[tid] = bh2a[tid]; }
    for (int i = tid; i < 16384; i += 512) {        // encW → LDS (stride 34)
        int row = i >> 5, s2 = i & 31;
        s_encW[row * 34 + s2] = g_encW2[(size_t)b * 16384 + i];
    }
    for (int i = tid; i < 4096; i += 512) {
        int s = i >> 6, a = i & 63;
        s_penc[s * 65 + a] = g_penc[((size_t)b * 64 + s) * 64 + a];
    }
    for (int i = tid; i < 8192; i += 512) {
        int d = i >> 6, s = i & 63;
        s_w2aT[s * 136 + d] = __float2bfloat16(W2a[i]);
    }
    float bal = balpha[0];

    const float* pre2p = g_pre2 + (size_t)b * TDIM * G4 + n;
    float* hwp0 = g_hw + (size_t)b * TDIM * 192;

    for (int t = 0; t < TDIM; ++t) {
        __syncthreads();                 // (1) h(t-1), wgt(t-1) ready; P landed
        float pre2v = pre2p[(size_t)t * G4];
        float acc0 = 0.f, acc1 = 0.f;
        const float4* vals = (const float4*)s_h;
        CONS1(P0,0)  CONS1(P1,1)  CONS1(P2,2)  CONS1(P3,3)
        CONS1(P4,4)  CONS1(P5,5)  CONS1(P6,6)  CONS1(P7,7)
        CONS1(P8,8)  CONS1(P9,9)  CONS1(P10,10) CONS1(P11,11)
        CONS1(P12,12) CONS1(P13,13) CONS1(P14,14) CONS1(P15,15)
        SB
        // prefetch h-half for t+1: lands during tail
        LDP(P0,0)  LDP(P1,1)  LDP(P2,2)  LDP(P3,3)
        LDP(P4,4)  LDP(P5,5)  LDP(P6,6)  LDP(P7,7)
        LDP(P8,8)  LDP(P9,9)  LDP(P10,10) LDP(P11,11)
        LDP(P12,12) LDP(P13,13) LDP(P14,14) LDP(P15,15)
        SB
        // wgt-half dot from LDS-resident encW (row n, b64 reads, 2-way banks)
        {
            const uint2* er = (const uint2*)(s_encW + n * 34);
            const float2* wg2 = (const float2*)s_wgt;
#pragma unroll
            for (int j = 0; j < 16; ++j) {
                uint2 ew = er[j];
                float2 wa = wg2[2 * j], wb = wg2[2 * j + 1];
                acc0 += bl(ew.x) * wa.x;  acc1 += bh(ew.x) * wa.y;
                acc0 += bl(ew.y) * wb.x;  acc1 += bh(ew.y) * wb.y;
            }
        }
        s_gates[n] = acc0 + acc1 + pre2v + (t ? bc_r : bias_r);
        __syncthreads();                 // (2) gates ready
        // LSTM pointwise (gate order i,f,g,o)
        if (tid < 128) {
            float gi = s_gates[tid];
            float gf = s_gates[tid + 128];
            float gg = s_gates[tid + 256];
            float go = s_gates[tid + 384];
            float c = sigm(gf) * s_c[tid] + sigm(gi) * tanh_fast(gg);
            s_c[tid] = c;
            float h = sigm(go) * tanh_fast(c);
            s_h[tid] = h;
            hwp0[(size_t)t * 192 + tid] = h;
        }
        __syncthreads();                 // (3) h ready
        // att_h[a] = h @ W2a[:,a] + bh2a[a] : 8-lane group per a
        {
            int a = tid >> 3, sub = tid & 7;
            const float4* hv4 = (const float4*)s_h;
            float4 h0 = hv4[4 * sub], h1 = hv4[4 * sub + 1],
                   h2 = hv4[4 * sub + 2], h3 = hv4[4 * sub + 3];
            uint4 w0 = *(const uint4*)&s_w2aT[a * 136 + 16 * sub];
            uint4 w1 = *(const uint4*)&s_w2aT[a * 136 + 16 * sub + 8];
            float acc = bl(w0.x) * h0.x + bh(w0.x) * h0.y +
                        bl(w0.y) * h0.z + bh(w0.y) * h0.w +
                        bl(w0.z) * h1.x + bh(w0.z) * h1.y +
                        bl(w0.w) * h1.z + bh(w0.w) * h1.w +
                        bl(w1.x) * h2.x + bh(w1.x) * h2.y +
                        bl(w1.y) * h2.z + bh(w1.y) * h2.w +
                        bl(w1.z) * h3.x + bh(w1.z) * h3.y +
                        bl(w1.w) * h3.z + bh(w1.w) * h3.w;
            acc += __shfl_xor(acc, 1);
            acc += __shfl_xor(acc, 2);
            acc += __shfl_xor(acc, 4);
            if (sub == 0) s_atth[a] = acc + s_bh2a[a];
        }
        __syncthreads();                 // (4) atth ready
        // scores[s] = sum_a tanh(p_enc + att_h) * W_alpha : 8 lanes per s
        {
            int ss = tid >> 3, sub = tid & 7;
            float acc = 0.f;
#pragma unroll
            for (int j = 0; j < 8; ++j) {
                int a = sub * 8 + j;
                float xv = s_penc[ss * 65 + a] + s_atth[a];
                acc += tanh_fast(xv) * s_walpha[a];
            }
            acc += __shfl_xor(acc, 1);
            acc += __shfl_xor(acc, 2);
            acc += __shfl_xor(acc, 4);
            if (sub == 0) s_scores[ss] = acc + bal;
        }
        __syncthreads();                 // (5) scores ready
        if (tid < 64) {                  // softmax → wgt (also stored for kD)
            float v = s_scores[tid];
            float m = v;
#pragma unroll
            for (int off = 32; off > 0; off >>= 1) m = fmaxf(m, __shfl_xor(m, off));
            float e = __expf(v - m);
            float sum = e;
#pragma unroll
            for (int off = 32; off > 0; off >>= 1) sum += __shfl_xor(sum, off);
            float w = e / sum;
            s_wgt[tid] = w;
            hwp0[(size_t)t * 192 + 128 + tid] = w;
        }
        // loop-top barrier covers s_wgt/s_h/s_gates reuse
    }
}

// ---- D: out = h@Wao_h + wgt@encWao[b] + bao ----
__global__ void kD(float* __restrict__ out) {
    int r = blockIdx.x * 4 + (threadIdx.x >> 6);
    int lane = threadIdx.x & 63;
    int b = r / TDIM;
    float acc[5] = {0.f, 0.f, 0.f, 0.f, 0.f};
    if (lane < 48) {
        const float4* hv = (const float4*)(g_hw + (size_t)r * 192);
        float4 v = hv[lane];
        int k0 = lane * 4;
        if (lane < 32) {
#pragma unroll
            for (int o = 0; o < 5; ++o)
                acc[o] = v.x * g_Wao[(k0 + 0) * 5 + o] + v.y * g_Wao[(k0 + 1) * 5 + o] +
                         v.z * g_Wao[(k0 + 2) * 5 + o] + v.w * g_Wao[(k0 + 3) * 5 + o];
        } else {
            int s0 = k0 - 128;
            const float* ew = g_encWao + ((size_t)b * 64 + s0) * 5;
#pragma unroll
            for (int o = 0; o < 5; ++o)
                acc[o] = v.x * ew[o] + v.y * ew[5 + o] + v.z * ew[10 + o] + v.w * ew[15 + o];
        }
    }
#pragma unroll
    for (int off = 32; off > 0; off >>= 1) {
#pragma unroll
        for (int o = 0; o < 5; ++o) acc[o] += __shfl_xor(acc[o], off);
    }
    if (lane == 0) {
#pragma unroll
        for (int o = 0; o < 5; ++o) out[(size_t)r * 5 + o] = acc[o] + g_bao[o];
    }
}

extern "C" void kernel_launch(void* const* d_in, const int* in_sizes, int n_in,
                              void* d_out, int out_size, void* d_ws, size_t ws_size,
                              hipStream_t stream) {
    (void)in_sizes; (void)n_in; (void)d_ws; (void)ws_size; (void)out_size;
    const float* tok  = (const float*)d_in[0];
    const float* feat = (const float*)d_in[1];
    const float* FH   = (const float*)d_in[2];
    const float* Wemb = (const float*)d_in[3];
    const float* bemb = (const float*)d_in[4];
    const float* Wih  = (const float*)d_in[5];
    const float* bih  = (const float*)d_in[6];
    const float* Whh  = (const float*)d_in[7];
    const float* bhh  = (const float*)d_in[8];
    const float* W2a  = (const float*)d_in[9];
    const float* bh2a = (const float*)d_in[10];
    const float* Wal  = (const float*)d_in[11];
    const float* bal  = (const float*)d_in[12];
    const float* Wep  = (const float*)d_in[13];
    const float* bep  = (const float*)d_in[14];
    const float* Waap = (const float*)d_in[15];
    const float* baap = (const float*)d_in[16];
    const float* Wout = (const float*)d_in[17];
    const float* bout = (const float*)d_in[18];
    float* out = (float*)d_out;

    const int kc_dyn_lds = 69632 + 16640 + 17408;    // 103680 B
    (void)hipFuncSetAttribute((const void*)kC,
                              hipFuncAttributeMaxDynamicSharedMemorySize,
                              kc_dyn_lds);

    kA1<<<dim3(BT / 4), dim3(256), 0, stream>>>(tok, feat, Wemb, bemb);
    kA2a<<<dim3(128), dim3(512), 0, stream>>>(Wih, Whh, Waap);
    kA2c<<<dim3(1), dim3(512), 0, stream>>>(bih, bhh, Wih, Waap, baap, Wout, bout);
    kA2d<<<dim3(64), dim3(256), 0, stream>>>(FH, Wep, bep);
    kA2e<<<dim3(BDIM), dim3(512), 0, stream>>>(FH);
    kB<<<dim3(BT / 8), dim3(512), 0, stream>>>(Wih);
    kC<<<dim3(64), dim3(512), kc_dyn_lds, stream>>>(Wal, bal, bh2a, W2a);
    kD<<<dim3(BT / 4), dim3(256), 0, stream>>>(out);
}